// Round 9
// baseline (348.505 us; speedup 1.0000x reference)
//
#include <hip/hip_runtime.h>

// ---------------------------------------------------------------------------
// EncoderLayer, MI355X gfx950. fp32 I/O, bf16 MFMA internally.
// r17: gemm256 -> m201-style 8-PHASE schedule (BK=64, 4 phases/tile):
//      LDS 128KB = 2buf x 2Khalf x [A 256x32 | B 256x32] (each half = the
//      r13-validated swizzled tile). Per phase: {ds_read quadrant || stage
//      ONE half-tile (2 gload_lds) -> s_barrier -> lgkmcnt(0) -> setprio(1)
//      16 MFMA setprio(0) -> s_barrier}. Staging 3 halves ahead:
//      tile T stages k1(T+1) in ph0/ph1, k0(T+2) in ph2/ph3.
//      WAR-safe (every slot restaged >=1 barrier after last read);
//      RAW-safe via ONE counted vmcnt(4) per tile before its final barrier
//      (never 0 mid-loop; 0 only at tail). r14's coarse-split regression is
//      the m196-predicted case; this is the fine interleave that gates T2/T5.
//      Everything else = r16 (345.8us: T1 swizzle, prep merge, attn r13).
// MFMA 16x16x32 bf16 layouts (m89/m91 verified):
//   A: lane holds A[m=lane&15][k=quad*8+j]; B: Bt[n=lane&15][k=quad*8+j]
//   C/D: reg r -> row=quad*4+r, col=lane&15
// Workspace (MB): 0-6 wqkvT | 6-8 woT | 8-16 w1T | 16-24 w2T | 24-32 ln |
//   32-48 qkb | 48-56 vbT | 56-64 ao | 64-80 x2 | 80-96 partials hi
// ---------------------------------------------------------------------------

typedef __attribute__((ext_vector_type(8))) unsigned short u16x8;
typedef __attribute__((ext_vector_type(4))) unsigned short u16x4;
typedef __attribute__((ext_vector_type(8))) __bf16 bf16x8;
typedef __attribute__((ext_vector_type(4))) float f32x4;
typedef __attribute__((ext_vector_type(4))) unsigned int u32x4;

#define C_SCALE 0.1803368801111f   // log2(e)/8 — folded into wk/bk

static __device__ __forceinline__ unsigned short f2b(float f) {
    return __builtin_bit_cast(unsigned short, (__bf16)f);
}
static __device__ __forceinline__ float b2f(unsigned short h) {
    unsigned u = ((unsigned)h) << 16;
    float f;
    __builtin_memcpy(&f, &u, 4);
    return f;
}

static __device__ __forceinline__ void async_cp16(
    const unsigned short* g, unsigned short* l)
{
    __builtin_amdgcn_global_load_lds(
        (const __attribute__((address_space(1))) unsigned int*)g,
        (__attribute__((address_space(3))) unsigned int*)l,
        16, 0, 0);
}

// ---------------------------------------------------------------------------
// Merged prep: blocks [0,12288) six weight transposes (fp32->bf16, [R][C]->
// [C][R]); [12288,12300) bias concat; [12300,16396) LayerNorm1 rows.
// Branch is blockIdx-uniform -> per-branch __syncthreads is legal.
// ---------------------------------------------------------------------------
__global__ __launch_bounds__(256) void prep_all_k(
    const float* __restrict__ wq, const float* __restrict__ wk,
    const float* __restrict__ wv, const float* __restrict__ wo,
    const float* __restrict__ w1, const float* __restrict__ w2,
    unsigned short* __restrict__ wqkvT, unsigned short* __restrict__ woT,
    unsigned short* __restrict__ w1T, unsigned short* __restrict__ w2T,
    const float* __restrict__ bq, const float* __restrict__ bk,
    const float* __restrict__ bv, float* __restrict__ bqkv,
    const float* __restrict__ x, const float* __restrict__ g1,
    const float* __restrict__ be1, unsigned short* __restrict__ lnout)
{
    __shared__ unsigned short tile[32][33];
    __shared__ float sb[4], ssb[4];
    const int ti = blockIdx.x;

    if (ti < 12288) {                       // ---- transposes ----
        const float* in;
        unsigned short* out;
        int R, C, bi, bj;
        float sc = 1.0f;
        if (ti < 4096) {
            R = 1024; C = 1024;
            bi = (ti & 1023) >> 5; bj = ti & 31;
            int z = ti >> 10;
            in = (z == 0) ? wq : (z == 1) ? wk : (z == 2) ? wv : wo;
            out = (z < 3) ? wqkvT + (size_t)z * 1024 * 1024 : woT;
            if (z == 1) sc = C_SCALE;
        } else if (ti < 8192) {
            R = 1024; C = 4096;
            int l = ti - 4096;
            bi = l >> 7; bj = l & 127;
            in = w1; out = w1T;
        } else {
            R = 4096; C = 1024;
            int l = ti - 8192;
            bi = l >> 5; bj = l & 31;
            in = w2; out = w2T;
        }
        const int tx = threadIdx.x & 31, ty = threadIdx.x >> 5;
#pragma unroll
        for (int rr = 0; rr < 4; ++rr) {
            int r = ty + rr * 8;
            tile[r][tx] = f2b(in[(size_t)(bi * 32 + r) * C + bj * 32 + tx] * sc);
        }
        __syncthreads();
#pragma unroll
        for (int rr = 0; rr < 4; ++rr) {
            int r = ty + rr * 8;
            out[(size_t)(bj * 32 + r) * R + bi * 32 + tx] = tile[tx][r];
        }
        return;
    }
    if (ti < 12300) {                       // ---- bias concat ----
        int t = (ti - 12288) * 256 + threadIdx.x;
        float v = (t < 1024) ? bq[t]
                : ((t < 2048) ? bk[t - 1024] * C_SCALE : bv[t - 2048]);
        bqkv[t] = v;
        return;
    }
    // ---- LayerNorm1 ----
    const int row = ti - 12300;
    const int t = threadIdx.x;
    const float* xr = x + (size_t)row * 1024;
    float4 v4 = *reinterpret_cast<const float4*>(&xr[t * 4]);
    float f[4] = {v4.x, v4.y, v4.z, v4.w};
    float s = f[0] + f[1] + f[2] + f[3];
    float ss = f[0] * f[0] + f[1] * f[1] + f[2] * f[2] + f[3] * f[3];
#pragma unroll
    for (int d = 1; d < 64; d <<= 1) {
        s += __shfl_xor(s, d);
        ss += __shfl_xor(ss, d);
    }
    const int wave = t >> 6;
    if ((t & 63) == 0) { sb[wave] = s; ssb[wave] = ss; }
    __syncthreads();
    s = sb[0] + sb[1] + sb[2] + sb[3];
    ss = ssb[0] + ssb[1] + ssb[2] + ssb[3];
    const float mu = s * (1.0f / 1024.0f);
    const float var = ss * (1.0f / 1024.0f) - mu * mu;
    const float rs = rsqrtf(var + 1e-5f);
    u16x4 r4;
#pragma unroll
    for (int j = 0; j < 4; ++j)
        r4[j] = f2b((f[j] - mu) * rs * g1[t * 4 + j] + be1[t * 4 + j]);
    *reinterpret_cast<u16x4*>(&lnout[(size_t)row * 1024 + t * 4]) = r4;
}

// ---------------------------------------------------------------------------
// Fused: x2 = sum(4 bf16 partials) + bias + x;  ln = LayerNorm(x2; g, be)
// ---------------------------------------------------------------------------
__global__ __launch_bounds__(256) void reduce_ln_kernel(
    const unsigned short* __restrict__ pa, const unsigned short* __restrict__ pb,
    const float* __restrict__ bias, const float* __restrict__ x,
    const float* __restrict__ g, const float* __restrict__ be,
    float* __restrict__ x2, unsigned short* __restrict__ o)
{
    const int row = blockIdx.x;
    const int t = threadIdx.x;
    const size_t base = (size_t)row * 1024 + t * 4;
    float4 x4 = *reinterpret_cast<const float4*>(&x[base]);
    float4 bb = *reinterpret_cast<const float4*>(&bias[t * 4]);
    float f[4] = {x4.x + bb.x, x4.y + bb.y, x4.z + bb.z, x4.w + bb.w};
#pragma unroll
    for (int z = 0; z < 2; ++z) {
        u16x4 va = *reinterpret_cast<const u16x4*>(&pa[(size_t)z * 4096 * 1024 + base]);
        u16x4 vb = *reinterpret_cast<const u16x4*>(&pb[(size_t)z * 4096 * 1024 + base]);
#pragma unroll
        for (int j = 0; j < 4; ++j) f[j] += b2f(va[j]) + b2f(vb[j]);
    }
    *reinterpret_cast<float4*>(&x2[base]) = {f[0], f[1], f[2], f[3]};
    float s = f[0] + f[1] + f[2] + f[3];
    float ss = f[0] * f[0] + f[1] * f[1] + f[2] * f[2] + f[3] * f[3];
#pragma unroll
    for (int d = 1; d < 64; d <<= 1) {
        s += __shfl_xor(s, d);
        ss += __shfl_xor(ss, d);
    }
    __shared__ float sb[4], ssb[4];
    const int wave = t >> 6;
    if ((t & 63) == 0) { sb[wave] = s; ssb[wave] = ss; }
    __syncthreads();
    s = sb[0] + sb[1] + sb[2] + sb[3];
    ss = ssb[0] + ssb[1] + ssb[2] + ssb[3];
    const float mu = s * (1.0f / 1024.0f);
    const float var = ss * (1.0f / 1024.0f) - mu * mu;
    const float rs = rsqrtf(var + 1e-5f);
    u16x4 r4;
#pragma unroll
    for (int j = 0; j < 4; ++j)
        r4[j] = f2b((f[j] - mu) * rs * g[t * 4 + j] + be[t * 4 + j]);
    *reinterpret_cast<u16x4*>(&o[base]) = r4;
}

// ---------------------------------------------------------------------------
// Fused final: out = sum(4 bf16 partials) + bias + x2
// ---------------------------------------------------------------------------
__global__ __launch_bounds__(256) void reduce_out4_k(
    const unsigned short* __restrict__ pa, const unsigned short* __restrict__ pb,
    const float* __restrict__ bias, const float* __restrict__ x2,
    float* __restrict__ out)
{
    const size_t i4 = ((size_t)blockIdx.x * 256 + threadIdx.x) * 4;
    float4 x4 = *reinterpret_cast<const float4*>(&x2[i4]);
    float4 bb = *reinterpret_cast<const float4*>(&bias[i4 & 1023]);
    float a0 = x4.x + bb.x, a1 = x4.y + bb.y, a2 = x4.z + bb.z, a3 = x4.w + bb.w;
#pragma unroll
    for (int z = 0; z < 2; ++z) {
        u16x4 va = *reinterpret_cast<const u16x4*>(&pa[(size_t)z * 4096 * 1024 + i4]);
        u16x4 vb = *reinterpret_cast<const u16x4*>(&pb[(size_t)z * 4096 * 1024 + i4]);
        a0 += b2f(va[0]) + b2f(vb[0]);
        a1 += b2f(va[1]) + b2f(vb[1]);
        a2 += b2f(va[2]) + b2f(vb[2]);
        a3 += b2f(va[3]) + b2f(vb[3]);
    }
    *reinterpret_cast<float4*>(&out[i4]) = {a0, a1, a2, a3};
}

// ---------------------------------------------------------------------------
// gemm256 r17 (8-phase): C[M][.] = A[M][lda] @ Bt[.][ldb]^T (+bias)(+ReLU)
// BM=BN=256, BK=64 (2 K-halves of 32), 512 threads, 8 waves (wm 2 x wn 4),
// per-wave 128x64. LDS 128KB: slot(buf,kh) = [A 256x32 | B 256x32], each a
// r13-style swizzled tile. Phases per tile: (kh0,mh0)(kh0,mh1)(kh1,mh0)
// (kh1,mh1), 16 MFMA each, 2 barriers each, lgkmcnt(0) before MFMA.
// Staging per phase (one matrix-half): ph0 A-k1(T+1), ph1 B-k1(T+1),
// ph2 A-k0(T+2), ph3 B-k0(T+2). vmcnt(4) (or 0 at tail) before final
// barrier of each tile. T1 XCD-bijective block swizzle (nwg%8==0 all sites).
// MODE 0: bf16 row-major (+ReLU); 2: fused QKV epilogue; 5: partial slices.
// ---------------------------------------------------------------------------
template<int MODE, int RELU>
__global__ __launch_bounds__(512, 1) void gemm256(
    const unsigned short* __restrict__ A, int lda,
    const unsigned short* __restrict__ Bt, int ldb,
    const float* __restrict__ bias,
    void* __restrict__ Cv, void* __restrict__ Cv2, int N, int Kloop)
{
    __shared__ unsigned short lds[4 * 16384];   // 128 KB
    const int t = threadIdx.x;
    const int wave = t >> 6, lane = t & 63;
    const int quad = lane >> 4, l16 = lane & 15;
    const int wm = wave >> 2, wn = wave & 3;
    // T1: XCD-chunked bijective remap of the xy block index
    const int nwg = gridDim.x * gridDim.y;
    const int id = blockIdx.y * gridDim.x + blockIdx.x;
    const int sw = (id & 7) * (nwg >> 3) + (id >> 3);
    const int m0 = (sw / gridDim.x) * 256;
    const int n0 = (sw % gridDim.x) * 256;
    const int k0 = blockIdx.z * Kloop;
    const int NT = Kloop >> 6;   // 64-wide K tiles

    // staging: thread t covers rows (t>>2) and (t>>2)+128 of a 256x32 half;
    // source colblk pre-swizzled (inverse of read swizzle)
    const int sc_row = t >> 2;
    const int sc_cb  = (t & 3) ^ ((t >> 3) & 3);
    const unsigned short* Abase = &A[(size_t)(m0 + sc_row) * lda + k0 + sc_cb * 8];
    const unsigned short* Bbase = &Bt[(size_t)(n0 + sc_row) * ldb + k0 + sc_cb * 8];
    const size_t Astep = (size_t)128 * lda;
    const size_t Bstep = (size_t)128 * ldb;

// stage one matrix-half: MAT 0=A 1=B, K-half kh of tile Tt -> its slot
#define SG(MAT, kh, Tt)                                                       \
    {                                                                         \
        unsigned short* d = &lds[(((Tt) & 1) * 2 + (kh)) * 16384 +            \
                                 ((MAT) ? 8192 : 0) + t * 8];                 \
        if (MAT) {                                                            \
            const unsigned short* s = Bbase + (Tt) * 64 + (kh) * 32;          \
            async_cp16(s, d);                                                 \
            async_cp16(s + Bstep, d + 4096);                                  \
        } else {                                                              \
            const unsigned short* s = Abase + (Tt) * 64 + (kh) * 32;          \
            async_cp16(s, d);                                                 \
            async_cp16(s + Astep, d + 4096);                                  \
        }                                                                     \
    }

    // fragment read offsets within a 256x32 slot (swizzled colblk)
    const int cb = quad ^ ((l16 >> 1) & 3);
    const int aoff = (wm * 128 + l16) * 32 + cb * 8;          // + mi*512
    const int boff = 8192 + (wn * 64 + l16) * 32 + cb * 8;    // + ni*512

    f32x4 acc[8][4];
#pragma unroll
    for (int mi = 0; mi < 8; ++mi)
#pragma unroll
        for (int ni = 0; ni < 4; ++ni) acc[mi][ni] = {0.f, 0.f, 0.f, 0.f};

    // prologue: tile0 fully + tile1's k0; wait tile0 (k0(1) stays in flight)
    SG(0, 0, 0); SG(1, 0, 0); SG(0, 1, 0); SG(1, 1, 0);
    if (NT > 1) {
        SG(0, 0, 1); SG(1, 0, 1);
        asm volatile("s_waitcnt vmcnt(4)\n\ts_barrier" ::: "memory");
    } else {
        asm volatile("s_waitcnt vmcnt(0)\n\ts_barrier" ::: "memory");
    }

    for (int T = 0; T < NT; ++T) {
        const unsigned short* L0 = &lds[((T & 1) * 2 + 0) * 16384];
        const unsigned short* L1 = &lds[((T & 1) * 2 + 1) * 16384];
        bf16x8 af[4], bfr[4];
        // ---- ph0: kh0, mi 0-3 ----
#pragma unroll
        for (int mi = 0; mi < 4; ++mi)
            af[mi] = __builtin_bit_cast(bf16x8,
                *reinterpret_cast<const u16x8*>(&L0[aoff + mi * 512]));
#pragma unroll
        for (int ni = 0; ni < 4; ++ni)
            bfr[ni] = __builtin_bit_cast(bf16x8,
                *reinterpret_cast<const u16x8*>(&L0[boff + ni * 512]));
        if (T + 1 < NT) SG(0, 1, T + 1);
        asm volatile("s_barrier\n\ts_waitcnt lgkmcnt(0)" ::: "memory");
        __builtin_amdgcn_s_setprio(1);
#pragma unroll
        for (int mi = 0; mi < 4; ++mi)
#pragma unroll
            for (int ni = 0; ni < 4; ++ni)
                acc[mi][ni] = __builtin_amdgcn_mfma_f32_16x16x32_bf16(
                    af[mi], bfr[ni], acc[mi][ni], 0, 0, 0);
        __builtin_amdgcn_s_setprio(0);
        asm volatile("s_barrier" ::: "memory");
        // ---- ph1: kh0, mi 4-7 (B frags reused) ----
#pragma unroll
        for (int mi = 0; mi < 4; ++mi)
            af[mi] = __builtin_bit_cast(bf16x8,
                *reinterpret_cast<const u16x8*>(&L0[aoff + (mi + 4) * 512]));
        if (T + 1 < NT) SG(1, 1, T + 1);
        asm volatile("s_barrier\n\ts_waitcnt lgkmcnt(0)" ::: "memory");
        __builtin_amdgcn_s_setprio(1);
#pragma unroll
        for (int mi = 0; mi < 4; ++mi)
#pragma unroll
            for (int ni = 0; ni < 4; ++ni)
                acc[mi + 4][ni] = __builtin_amdgcn_mfma_f32_16x16x32_bf16(
                    af[mi], bfr[ni], acc[mi + 4][ni], 0, 0, 0);
        __builtin_amdgcn_s_setprio(0);
        asm volatile("s_barrier" ::: "memory");
        // ---- ph2: kh1, mi 0-3 ----
#pragma unroll
        for (int mi = 0; mi < 4; ++mi)
            af[mi] = __builtin_bit_cast(bf16x8,
                *reinterpret_cast<const u16x8*>(&L1[aoff + mi * 512]));
#pragma unroll
        for (int ni = 0; ni < 4; ++ni)
            bfr[ni] = __builtin_bit_cast(bf16x8,
                *reinterpret_cast<const u16x8*>(&L1[boff + ni * 512]));
        if (T + 2 < NT) SG(0, 0, T + 2);
        asm volatile("s_barrier\n\ts_waitcnt lgkmcnt(0)" ::: "memory");
        __builtin_amdgcn_s_setprio(1);
#pragma unroll
        for (int mi = 0; mi < 4; ++mi)
#pragma unroll
            for (int ni = 0; ni < 4; ++ni)
                acc[mi][ni] = __builtin_amdgcn_mfma_f32_16x16x32_bf16(
                    af[mi], bfr[ni], acc[mi][ni], 0, 0, 0);
        __builtin_amdgcn_s_setprio(0);
        asm volatile("s_barrier" ::: "memory");
        // ---- ph3: kh1, mi 4-7 ----
#pragma unroll
        for (int mi = 0; mi < 4; ++mi)
            af[mi] = __builtin_bit_cast(bf16x8,
                *reinterpret_cast<const u16x8*>(&L1[aoff + (mi + 4) * 512]));
        if (T + 2 < NT) SG(1, 0, T + 2);
        asm volatile("s_barrier\n\ts_waitcnt lgkmcnt(0)" ::: "memory");
        __builtin_amdgcn_s_setprio(1);
#pragma unroll
        for (int mi = 0; mi < 4; ++mi)
#pragma unroll
            for (int ni = 0; ni < 4; ++ni)
                acc[mi + 4][ni] = __builtin_amdgcn_mfma_f32_16x16x32_bf16(
                    af[mi], bfr[ni], acc[mi + 4][ni], 0, 0, 0);
        __builtin_amdgcn_s_setprio(0);
        // tile boundary: everything tile T+1 reads (k0,k1 of T+1) must have
        // landed; only k0(T+2)'s 4 loads may remain in flight.
        if (T + 1 < NT) {
            if (T + 2 < NT)
                asm volatile("s_waitcnt vmcnt(4)\n\ts_barrier" ::: "memory");
            else
                asm volatile("s_waitcnt vmcnt(0)\n\ts_barrier" ::: "memory");
        }
    }
#undef SG

#pragma unroll
    for (int mi = 0; mi < 8; ++mi) {
        const int gr0 = m0 + wm * 128 + mi * 16 + quad * 4;
#pragma unroll
        for (int ni = 0; ni < 4; ++ni) {
            const int gc = n0 + wn * 64 + ni * 16 + l16;
            if (MODE == 2) {
                const float bv = bias[gc];
                if (gc < 2048) {
#pragma unroll
                    for (int r = 0; r < 4; ++r)
                        ((unsigned short*)Cv)[(size_t)(gr0 + r) * 2048 + gc] =
                            f2b(acc[mi][ni][r] + bv);
                } else {
                    u16x4 pk;
#pragma unroll
                    for (int r = 0; r < 4; ++r) pk[r] = f2b(acc[mi][ni][r] + bv);
                    const int bb = gr0 >> 11, s0 = gr0 & 2047;
                    *reinterpret_cast<u16x4*>(
                        &((unsigned short*)Cv2)[((size_t)bb * 1024 + (gc - 2048)) * 2048 + s0]) = pk;
                }
            } else if (MODE == 5) {
                unsigned short* base = (blockIdx.z < 2)
                    ? (unsigned short*)Cv  + (size_t)blockIdx.z * 4096 * N
                    : (unsigned short*)Cv2 + (size_t)(blockIdx.z - 2) * 4096 * N;
#pragma unroll
                for (int r = 0; r < 4; ++r)
                    base[(size_t)(gr0 + r) * N + gc] = f2b(acc[mi][ni][r]);
            } else {
                const float bv = bias[gc];
#pragma unroll
                for (int r = 0; r < 4; ++r) {
                    float v = acc[mi][ni][r] + bv;
                    if (RELU) v = fmaxf(v, 0.f);
                    ((unsigned short*)Cv)[(size_t)(gr0 + r) * N + gc] = f2b(v);
                }
            }
        }
    }
}

// ---------------------------------------------------------------------------
// Flash attention, r13 (kept — at its multi-pipe floor, 0 conflicts).
// K pre-scaled by log2(e)/8 -> p = exp2(s). qkb: [4096][2048]; vbT V^T.
// Grid (16, 32): 128 q/block, 4 waves x 32 q. DMA staging into TRIPLE-
// buffered swizzled LDS, counted vmcnt(4), one barrier per tile.
// S^T via mfma(A=K, B=Q); PV A-frag via permlane swaps; l via ones-MFMA.
// ---------------------------------------------------------------------------
__global__ __launch_bounds__(256, 2) void attn_kernel(
    const unsigned short* __restrict__ qkb, const unsigned short* __restrict__ vbT,
    unsigned short* __restrict__ ao)
{
    __shared__ unsigned short lds[3 * 8192];   // [buf][K 4096 | V 4096] elems
    const int t = threadIdx.x;
    const int lane = t & 63;
    const int quad = lane >> 4, l16 = lane & 15;
    const int wave = t >> 6;
    const int bh = blockIdx.y;
    const int b = bh >> 4, h = bh & 15;
    const int q0 = blockIdx.x * 128 + wave * 32;
    const size_t qk_base = (size_t)b * 2048 * 2048;
    const size_t vt_base = (size_t)b * 1024 * 2048 + (size_t)h * 64 * 2048;

    // Q as B-operand: lane holds Q[q=l16 (+16m)][d=quad*8+j (+32kk)]
    bf16x8 qf[2][2];
#pragma unroll
    for (int m = 0; m < 2; ++m)
#pragma unroll
        for (int kk = 0; kk < 2; ++kk)
            qf[m][kk] = __builtin_bit_cast(bf16x8, *reinterpret_cast<const u16x8*>(
                &qkb[qk_base + (size_t)(q0 + m * 16 + l16) * 2048 + h * 64 + kk * 32 + quad * 8]));

    // ones fragment (bf16 1.0 = 0x3F80) for l = P @ 1
    u16x8 ones_u;
#pragma unroll
    for (int j = 0; j < 8; ++j) ones_u[j] = 0x3F80;
    const bf16x8 onesf = __builtin_bit_cast(bf16x8, ones_u);

    f32x4 o_acc[2][4], l_frag[2];
#pragma unroll
    for (int m = 0; m < 2; ++m) {
        l_frag[m] = {0.f, 0.f, 0.f, 0.f};
#pragma unroll
        for (int nf = 0; nf < 4; ++nf) o_acc[m][nf] = {0.f, 0.f, 0.f, 0.f};
    }

    // staging: chunk c (c0=t, c1=t+256): row=c>>3, src colblk=(c&7)^(row&7)
    const int c0 = t, c1 = t + 256;
    const int r0 = c0 >> 3, r1 = c1 >> 3;
    const int scb0 = (c0 & 7) ^ (r0 & 7), scb1 = (c1 & 7) ^ (r1 & 7);
    const unsigned short* kS0 = &qkb[qk_base + (size_t)r0 * 2048 + 1024 + h * 64 + scb0 * 8];
    const unsigned short* kS1 = &qkb[qk_base + (size_t)r1 * 2048 + 1024 + h * 64 + scb1 * 8];
    const unsigned short* vS0 = &vbT[vt_base + (size_t)r0 * 2048 + scb0 * 8];
    const unsigned short* vS1 = &vbT[vt_base + (size_t)r1 * 2048 + scb1 * 8];

    // fragment read base: row l16, swizzled colblk (quad ^ (l16&7))
    const int off0 = l16 * 64 + ((quad ^ (l16 & 7)) * 8);

#define STAGE(tile, buf)                                                      \
    {                                                                         \
        const size_t ko = (size_t)(tile) * 64 * 2048;                         \
        const int vo = (tile) * 64;                                           \
        async_cp16(kS0 + ko, &lds[(buf) * 8192 + c0 * 8]);                    \
        async_cp16(kS1 + ko, &lds[(buf) * 8192 + c1 * 8]);                    \
        async_cp16(vS0 + vo, &lds[(buf) * 8192 + 4096 + c0 * 8]);             \
        async_cp16(vS1 + vo, &lds[(buf) * 8192 + 4096 + c1 * 8]);             \
    }

    // prologue: tile0 -> buf0, tile1 -> buf1; wait tile0 (4 still in flight)
    STAGE(0, 0);
    STAGE(1, 1);
    asm volatile("s_waitcnt vmcnt(4)\n\ts_barrier" ::: "memory");

    for (int tt = 0; tt < 32; ++tt) {
        const int buf = tt - (tt / 3) * 3;
        const int pf = tt + 2;
        if (pf < 32) {
            const int bp = pf - (pf / 3) * 3;
            STAGE(pf, bp);
        }
        const unsigned short* LK = &lds[buf * 8192];
        const unsigned short* LV = LK + 4096;

        // S^T for the four 16-key fragments of this 64-key tile
        unsigned d0[2][4], d1[2][4];   // [m][kf]
#pragma unroll
        for (int kf = 0; kf < 4; ++kf) {
            bf16x8 kfr0 = __builtin_bit_cast(bf16x8,
                *reinterpret_cast<const u16x8*>(&LK[off0 + kf * 1024]));
            bf16x8 kfr1 = __builtin_bit_cast(bf16x8,
                *reinterpret_cast<const u16x8*>(&LK[(off0 ^ 32) + kf * 1024]));
#pragma unroll
            for (int m = 0; m < 2; ++m) {
                f32x4 s = {0.f, 0.f, 0.f, 0.f};
                s = __builtin_amdgcn_mfma_f32_16x16x32_bf16(kfr0, qf[m][0], s, 0, 0, 0);
                s = __builtin_amdgcn_mfma_f32_16x16x32_bf16(kfr1, qf[m][1], s, 0, 0, 0);
                d0[m][kf] = (unsigned)f2b(exp2f(s[0])) |
                            ((unsigned)f2b(exp2f(s[1])) << 16);
                d1[m][kf] = (unsigned)f2b(exp2f(s[2])) |
                            ((unsigned)f2b(exp2f(s[3])) << 16);
            }
        }
#pragma unroll
        for (int kh = 0; kh < 2; ++kh) {
            bf16x8 pfr[2];
#pragma unroll
            for (int m = 0; m < 2; ++m) {
                unsigned x0 = d0[m][kh * 2], y0 = d0[m][kh * 2 + 1];
                unsigned x1 = d1[m][kh * 2], y1 = d1[m][kh * 2 + 1];
                asm("v_permlane32_swap_b32 %0, %1\n\t"
                    "v_permlane16_swap_b32 %0, %1"
                    : "+v"(x0), "+v"(y0));
                asm("v_permlane32_swap_b32 %0, %1\n\t"
                    "v_permlane16_swap_b32 %0, %1"
                    : "+v"(x1), "+v"(y1));
                u32x4 pw = {x0, x1, y0, y1};   // W0,W1,W2,W3
                pfr[m] = __builtin_bit_cast(bf16x8, pw);
                l_frag[m] = __builtin_amdgcn_mfma_f32_16x16x32_bf16(
                    pfr[m], onesf, l_frag[m], 0, 0, 0);
            }
            __builtin_amdgcn_s_setprio(1);
#pragma unroll
            for (int nf = 0; nf < 4; ++nf) {
                bf16x8 vfr = __builtin_bit_cast(bf16x8,
                    *reinterpret_cast<const u16x8*>(&LV[(off0 ^ (kh * 32)) + nf * 1024]));
#pragma unroll
                for (int m = 0; m < 2; ++m)
                    o_acc[m][nf] = __builtin_amdgcn_mfma_f32_16x16x32_bf16(
                        pfr[m], vfr, o_acc[m][nf], 0, 0, 0);
            }
            __builtin_amdgcn_s_setprio(0);
        }
        // boundary: tile tt+1 visible after barrier; tile tt+2 still in flight
        if (tt + 1 < 32) {
            if (pf < 32)
                asm volatile("s_waitcnt vmcnt(4)\n\ts_barrier" ::: "memory");
            else
                asm volatile("s_waitcnt vmcnt(0)\n\ts_barrier" ::: "memory");
        }
    }
#undef STAGE

    // store: o_acc rows q = q0 + m*16 + quad*4 + r; l_frag rows align.
#pragma unroll
    for (int m = 0; m < 2; ++m) {
#pragma unroll
        for (int r = 0; r < 4; ++r) {
            const float inv = 1.0f / l_frag[m][r];
            const int row = q0 + m * 16 + quad * 4 + r;
#pragma unroll
            for (int nf = 0; nf < 4; ++nf)
                ao[(size_t)b * 2048 * 1024 + (size_t)row * 1024 + h * 64 + nf * 16 + l16] =
                    f2b(o_acc[m][nf][r] * inv);
        }
    }
}

// ---------------------------------------------------------------------------
extern "C" void kernel_launch(void* const* d_in, const int* in_sizes, int n_in,
                              void* d_out, int out_size, void* d_ws, size_t ws_size,
                              hipStream_t stream)
{
    const float* x   = (const float*)d_in[0];
    const float* wq  = (const float*)d_in[1];
    const float* bq  = (const float*)d_in[2];
    const float* wk  = (const float*)d_in[3];
    const float* bk  = (const float*)d_in[4];
    const float* wv  = (const float*)d_in[5];
    const float* bv  = (const float*)d_in[6];
    const float* wo  = (const float*)d_in[7];
    const float* bo  = (const float*)d_in[8];
    const float* w1  = (const float*)d_in[9];
    const float* b1  = (const float*)d_in[10];
    const float* w2  = (const float*)d_in[11];
    const float* b2  = (const float*)d_in[12];
    const float* g1  = (const float*)d_in[13];
    const float* be1 = (const float*)d_in[14];
    const float* g2  = (const float*)d_in[15];
    const float* be2 = (const float*)d_in[16];
    float* out = (float*)d_out;
    char*  ws  = (char*)d_ws;

    const int M = 4096, D = 1024, DFF = 4096;
    const size_t MB = 1 << 20;

    unsigned short* wqkvT = (unsigned short*)(ws + 0 * MB);   // [3072][1024] 6MB
    unsigned short* woT   = (unsigned short*)(ws + 6 * MB);   // 2MB
    unsigned short* w1T   = (unsigned short*)(ws + 8 * MB);   // 8MB
    unsigned short* w2T   = (unsigned short*)(ws + 16 * MB);  // 8MB
    unsigned short* ln    = (unsigned short*)(ws + 24 * MB);  // 8MB
    unsigned short* qkb   = (unsigned short*)(ws + 32 * MB);  // 16MB
    unsigned short* vbT   = (unsigned short*)(ws + 48 * MB);  // 8MB
    unsigned short* ao    = (unsigned short*)(ws + 56 * MB);  // 8MB
    unsigned short* ff1   = (unsigned short*)(ws + 32 * MB);  // 32MB (reuse)
    float*          x2    = (float*)(ws + 64 * MB);           // 16MB
    float*          bqkv  = (float*)(ws + 80 * MB);           // 12KB (pre-partials)
    unsigned short* pHi   = (unsigned short*)(ws + 80 * MB);  // slices 0,1 (16MB)
    unsigned short* pOlo  = (unsigned short*)(ws + 32 * MB);  // O-proj slices 2,3
    unsigned short* pFlo  = (unsigned short*)(ws + 0 * MB);   // FF2 slices 2,3

    // --- weight prep + bias concat + LN1 (one launch) ---
    prep_all_k<<<16396, 256, 0, stream>>>(wq, wk, wv, wo, w1, w2,
                                          wqkvT, woT, w1T, w2T,
                                          bq, bk, bv, bqkv,
                                          x, g1, be1, ln);
    // --- fused QKV projection: QK' -> qkb, V -> vbT (V^T) ---
    gemm256<2, 0><<<dim3(12, 16), 512, 0, stream>>>(
        ln, D, wqkvT, D, bqkv, qkb, vbT, 3072, D);
    // --- attention ---
    attn_kernel<<<dim3(16, 32), 256, 0, stream>>>(qkb, vbT, ao);
    // --- O projection split-K4 bf16 partials; reduce + residual + LN2 ---
    gemm256<5, 0><<<dim3(4, 16, 4), 512, 0, stream>>>(
        ao, D, woT, D, nullptr, pHi, pOlo, 1024, 256);
    reduce_ln_kernel<<<M, 256, 0, stream>>>(pHi, pOlo, bo, x, g2, be2, x2, ln);
    // --- FFN ---
    gemm256<0, 1><<<dim3(16, 16), 512, 0, stream>>>(
        ln, D, w1T, D, b1, ff1, nullptr, DFF, D);
    gemm256<5, 0><<<dim3(4, 16, 4), 512, 0, stream>>>(
        ff1, DFF, w2T, DFF, nullptr, pHi, pFlo, 1024, 1024);
    reduce_out4_k<<<4096, 256, 0, stream>>>(pHi, pFlo, b2, x2, out);
}

// Round 10
// 344.126 us; speedup vs baseline: 1.0127x; 1.0127x over previous
//
#include <hip/hip_runtime.h>

// ---------------------------------------------------------------------------
// EncoderLayer, MI355X gfx950. fp32 I/O, bf16 MFMA internally.
// r18 = r16 verbatim (measured best, 345.8us). Session summary:
//   r12: gemm256 256^2 BK=32 TRIPLE-buffer + counted vmcnt(4) (+21us)
//   r13: attn DMA staging + swizzle + counted vmcnt, 0 conflicts (+4us)
//   r16: T1 XCD-bijective block swizzle + prep merge (+8us)
//   Falsified: BK=64 drain-0 (r14), full-K 128^2 (r15), 8-phase (r17) —
//   deep pipelining does not pay at NT=4..16 / L3-resident GEMM sizes.
//   attn chain-bound (~72-77us) across 6 structural variants; all pipes <55%.
// MFMA 16x16x32 bf16 layouts (m89/m91 verified):
//   A: lane holds A[m=lane&15][k=quad*8+j]; B: Bt[n=lane&15][k=quad*8+j]
//   C/D: reg r -> row=quad*4+r, col=lane&15
// Workspace (MB): 0-6 wqkvT | 6-8 woT | 8-16 w1T | 16-24 w2T | 24-32 ln |
//   32-48 qkb | 48-56 vbT | 56-64 ao | 64-80 x2 | 80-96 partials hi
// ---------------------------------------------------------------------------

typedef __attribute__((ext_vector_type(8))) unsigned short u16x8;
typedef __attribute__((ext_vector_type(4))) unsigned short u16x4;
typedef __attribute__((ext_vector_type(8))) __bf16 bf16x8;
typedef __attribute__((ext_vector_type(4))) float f32x4;
typedef __attribute__((ext_vector_type(4))) unsigned int u32x4;

#define C_SCALE 0.1803368801111f   // log2(e)/8 — folded into wk/bk

static __device__ __forceinline__ unsigned short f2b(float f) {
    return __builtin_bit_cast(unsigned short, (__bf16)f);
}
static __device__ __forceinline__ float b2f(unsigned short h) {
    unsigned u = ((unsigned)h) << 16;
    float f;
    __builtin_memcpy(&f, &u, 4);
    return f;
}

static __device__ __forceinline__ void async_cp16(
    const unsigned short* g, unsigned short* l)
{
    __builtin_amdgcn_global_load_lds(
        (const __attribute__((address_space(1))) unsigned int*)g,
        (__attribute__((address_space(3))) unsigned int*)l,
        16, 0, 0);
}

// ---------------------------------------------------------------------------
// Merged prep: blocks [0,12288) six weight transposes (fp32->bf16, [R][C]->
// [C][R]); [12288,12300) bias concat; [12300,16396) LayerNorm1 rows.
// Branch is blockIdx-uniform -> per-branch __syncthreads is legal.
// ---------------------------------------------------------------------------
__global__ __launch_bounds__(256) void prep_all_k(
    const float* __restrict__ wq, const float* __restrict__ wk,
    const float* __restrict__ wv, const float* __restrict__ wo,
    const float* __restrict__ w1, const float* __restrict__ w2,
    unsigned short* __restrict__ wqkvT, unsigned short* __restrict__ woT,
    unsigned short* __restrict__ w1T, unsigned short* __restrict__ w2T,
    const float* __restrict__ bq, const float* __restrict__ bk,
    const float* __restrict__ bv, float* __restrict__ bqkv,
    const float* __restrict__ x, const float* __restrict__ g1,
    const float* __restrict__ be1, unsigned short* __restrict__ lnout)
{
    __shared__ unsigned short tile[32][33];
    __shared__ float sb[4], ssb[4];
    const int ti = blockIdx.x;

    if (ti < 12288) {                       // ---- transposes ----
        const float* in;
        unsigned short* out;
        int R, C, bi, bj;
        float sc = 1.0f;
        if (ti < 4096) {
            R = 1024; C = 1024;
            bi = (ti & 1023) >> 5; bj = ti & 31;
            int z = ti >> 10;
            in = (z == 0) ? wq : (z == 1) ? wk : (z == 2) ? wv : wo;
            out = (z < 3) ? wqkvT + (size_t)z * 1024 * 1024 : woT;
            if (z == 1) sc = C_SCALE;
        } else if (ti < 8192) {
            R = 1024; C = 4096;
            int l = ti - 4096;
            bi = l >> 7; bj = l & 127;
            in = w1; out = w1T;
        } else {
            R = 4096; C = 1024;
            int l = ti - 8192;
            bi = l >> 5; bj = l & 31;
            in = w2; out = w2T;
        }
        const int tx = threadIdx.x & 31, ty = threadIdx.x >> 5;
#pragma unroll
        for (int rr = 0; rr < 4; ++rr) {
            int r = ty + rr * 8;
            tile[r][tx] = f2b(in[(size_t)(bi * 32 + r) * C + bj * 32 + tx] * sc);
        }
        __syncthreads();
#pragma unroll
        for (int rr = 0; rr < 4; ++rr) {
            int r = ty + rr * 8;
            out[(size_t)(bj * 32 + r) * R + bi * 32 + tx] = tile[tx][r];
        }
        return;
    }
    if (ti < 12300) {                       // ---- bias concat ----
        int t = (ti - 12288) * 256 + threadIdx.x;
        float v = (t < 1024) ? bq[t]
                : ((t < 2048) ? bk[t - 1024] * C_SCALE : bv[t - 2048]);
        bqkv[t] = v;
        return;
    }
    // ---- LayerNorm1 ----
    const int row = ti - 12300;
    const int t = threadIdx.x;
    const float* xr = x + (size_t)row * 1024;
    float4 v4 = *reinterpret_cast<const float4*>(&xr[t * 4]);
    float f[4] = {v4.x, v4.y, v4.z, v4.w};
    float s = f[0] + f[1] + f[2] + f[3];
    float ss = f[0] * f[0] + f[1] * f[1] + f[2] * f[2] + f[3] * f[3];
#pragma unroll
    for (int d = 1; d < 64; d <<= 1) {
        s += __shfl_xor(s, d);
        ss += __shfl_xor(ss, d);
    }
    const int wave = t >> 6;
    if ((t & 63) == 0) { sb[wave] = s; ssb[wave] = ss; }
    __syncthreads();
    s = sb[0] + sb[1] + sb[2] + sb[3];
    ss = ssb[0] + ssb[1] + ssb[2] + ssb[3];
    const float mu = s * (1.0f / 1024.0f);
    const float var = ss * (1.0f / 1024.0f) - mu * mu;
    const float rs = rsqrtf(var + 1e-5f);
    u16x4 r4;
#pragma unroll
    for (int j = 0; j < 4; ++j)
        r4[j] = f2b((f[j] - mu) * rs * g1[t * 4 + j] + be1[t * 4 + j]);
    *reinterpret_cast<u16x4*>(&lnout[(size_t)row * 1024 + t * 4]) = r4;
}

// ---------------------------------------------------------------------------
// Fused: x2 = sum(4 bf16 partials) + bias + x;  ln = LayerNorm(x2; g, be)
// ---------------------------------------------------------------------------
__global__ __launch_bounds__(256) void reduce_ln_kernel(
    const unsigned short* __restrict__ pa, const unsigned short* __restrict__ pb,
    const float* __restrict__ bias, const float* __restrict__ x,
    const float* __restrict__ g, const float* __restrict__ be,
    float* __restrict__ x2, unsigned short* __restrict__ o)
{
    const int row = blockIdx.x;
    const int t = threadIdx.x;
    const size_t base = (size_t)row * 1024 + t * 4;
    float4 x4 = *reinterpret_cast<const float4*>(&x[base]);
    float4 bb = *reinterpret_cast<const float4*>(&bias[t * 4]);
    float f[4] = {x4.x + bb.x, x4.y + bb.y, x4.z + bb.z, x4.w + bb.w};
#pragma unroll
    for (int z = 0; z < 2; ++z) {
        u16x4 va = *reinterpret_cast<const u16x4*>(&pa[(size_t)z * 4096 * 1024 + base]);
        u16x4 vb = *reinterpret_cast<const u16x4*>(&pb[(size_t)z * 4096 * 1024 + base]);
#pragma unroll
        for (int j = 0; j < 4; ++j) f[j] += b2f(va[j]) + b2f(vb[j]);
    }
    *reinterpret_cast<float4*>(&x2[base]) = {f[0], f[1], f[2], f[3]};
    float s = f[0] + f[1] + f[2] + f[3];
    float ss = f[0] * f[0] + f[1] * f[1] + f[2] * f[2] + f[3] * f[3];
#pragma unroll
    for (int d = 1; d < 64; d <<= 1) {
        s += __shfl_xor(s, d);
        ss += __shfl_xor(ss, d);
    }
    __shared__ float sb[4], ssb[4];
    const int wave = t >> 6;
    if ((t & 63) == 0) { sb[wave] = s; ssb[wave] = ss; }
    __syncthreads();
    s = sb[0] + sb[1] + sb[2] + sb[3];
    ss = ssb[0] + ssb[1] + ssb[2] + ssb[3];
    const float mu = s * (1.0f / 1024.0f);
    const float var = ss * (1.0f / 1024.0f) - mu * mu;
    const float rs = rsqrtf(var + 1e-5f);
    u16x4 r4;
#pragma unroll
    for (int j = 0; j < 4; ++j)
        r4[j] = f2b((f[j] - mu) * rs * g[t * 4 + j] + be[t * 4 + j]);
    *reinterpret_cast<u16x4*>(&o[base]) = r4;
}

// ---------------------------------------------------------------------------
// Fused final: out = sum(4 bf16 partials) + bias + x2
// ---------------------------------------------------------------------------
__global__ __launch_bounds__(256) void reduce_out4_k(
    const unsigned short* __restrict__ pa, const unsigned short* __restrict__ pb,
    const float* __restrict__ bias, const float* __restrict__ x2,
    float* __restrict__ out)
{
    const size_t i4 = ((size_t)blockIdx.x * 256 + threadIdx.x) * 4;
    float4 x4 = *reinterpret_cast<const float4*>(&x2[i4]);
    float4 bb = *reinterpret_cast<const float4*>(&bias[i4 & 1023]);
    float a0 = x4.x + bb.x, a1 = x4.y + bb.y, a2 = x4.z + bb.z, a3 = x4.w + bb.w;
#pragma unroll
    for (int z = 0; z < 2; ++z) {
        u16x4 va = *reinterpret_cast<const u16x4*>(&pa[(size_t)z * 4096 * 1024 + i4]);
        u16x4 vb = *reinterpret_cast<const u16x4*>(&pb[(size_t)z * 4096 * 1024 + i4]);
        a0 += b2f(va[0]) + b2f(vb[0]);
        a1 += b2f(va[1]) + b2f(vb[1]);
        a2 += b2f(va[2]) + b2f(vb[2]);
        a3 += b2f(va[3]) + b2f(vb[3]);
    }
    *reinterpret_cast<float4*>(&out[i4]) = {a0, a1, a2, a3};
}

// ---------------------------------------------------------------------------
// gemm256 (r13 + T1): C[M][.] = A[M][lda] @ Bt[.][ldb]^T (+bias)(+ReLU)
// BM=BN=256, BK=32, 512 threads (8 waves: wm=w>>2, wn=w&3), per-wave 128x64.
// Triple-buffered LDS (96KB), counted vmcnt(4) boundary + ONE barrier per
// K-tile. T2 swizzle both sides. T1: XCD-bijective blockIdx swizzle
// (requires gridDim.x*gridDim.y % 8 == 0 — true for all call sites).
// MODE 0: bf16 row-major (+ReLU); 2: fused QKV epilogue; 5: partial slices.
// ---------------------------------------------------------------------------
template<int MODE, int RELU>
__global__ __launch_bounds__(512, 1) void gemm256(
    const unsigned short* __restrict__ A, int lda,
    const unsigned short* __restrict__ Bt, int ldb,
    const float* __restrict__ bias,
    void* __restrict__ Cv, void* __restrict__ Cv2, int N, int Kloop)
{
    __shared__ unsigned short lds[3 * 16384];   // 96 KB
    const int t = threadIdx.x;
    const int wave = t >> 6, lane = t & 63;
    const int quad = lane >> 4, l16 = lane & 15;
    const int wm = wave >> 2, wn = wave & 3;
    // T1: XCD-chunked bijective remap of the xy block index
    const int nwg = gridDim.x * gridDim.y;
    const int id = blockIdx.y * gridDim.x + blockIdx.x;
    const int sw = (id & 7) * (nwg >> 3) + (id >> 3);
    const int m0 = (sw / gridDim.x) * 256;
    const int n0 = (sw % gridDim.x) * 256;
    const int k0 = blockIdx.z * Kloop;
    const int NT = Kloop >> 5;

    // staging: thread t covers row ph*128 + (t>>2), source colblk pre-swizzled
    const int sc_row = t >> 2;
    const int sc_cb  = (t & 3) ^ ((t >> 3) & 3);
    const unsigned short* Asrc = &A[(size_t)(m0 + sc_row) * lda + k0 + sc_cb * 8];
    const unsigned short* Bsrc = &Bt[(size_t)(n0 + sc_row) * ldb + k0 + sc_cb * 8];
    const size_t Astep = (size_t)128 * lda;
    const size_t Bstep = (size_t)128 * ldb;
    unsigned short* dstA = &lds[t * 8];
    unsigned short* dstB = &lds[8192 + t * 8];

    // fragment read offsets (swizzled colblk, constant per lane)
    const int cb = quad ^ ((l16 >> 1) & 3);
    const int aoff = (wm * 128 + l16) * 32 + cb * 8;          // + mi*512
    const int boff = 8192 + (wn * 64 + l16) * 32 + cb * 8;    // + ni*512

    f32x4 acc[8][4];
#pragma unroll
    for (int mi = 0; mi < 8; ++mi)
#pragma unroll
        for (int ni = 0; ni < 4; ++ni) acc[mi][ni] = {0.f, 0.f, 0.f, 0.f};

    // prologue: stage tile0 -> buf0, tile1 -> buf1
    async_cp16(Asrc, dstA);
    async_cp16(Asrc + Astep, dstA + 4096);
    async_cp16(Bsrc, dstB);
    async_cp16(Bsrc + Bstep, dstB + 4096);
    if (NT > 1) {
        async_cp16(Asrc + 32, dstA + 16384);
        async_cp16(Asrc + Astep + 32, dstA + 16384 + 4096);
        async_cp16(Bsrc + 32, dstB + 16384);
        async_cp16(Bsrc + Bstep + 32, dstB + 16384 + 4096);
        asm volatile("s_waitcnt vmcnt(4)\n\ts_barrier" ::: "memory");
    } else {
        asm volatile("s_waitcnt vmcnt(0)\n\ts_barrier" ::: "memory");
    }

    for (int tt = 0; tt < NT; ++tt) {
        const int b = tt - (tt / 3) * 3;
        const unsigned short* Lb = &lds[b * 16384];
        const int pf = tt + 2;
        const int bp = (pf < NT) ? (pf - (pf / 3) * 3) * 16384 : 0;
        bf16x8 af[8], bfr[4];
        // ---- phase 1: stage A(t+2); read A frags + B n0,n1; MFMA half ----
        if (pf < NT) {
            async_cp16(Asrc + (size_t)pf * 32, &lds[bp] + t * 8);
            async_cp16(Asrc + Astep + (size_t)pf * 32, &lds[bp] + t * 8 + 4096);
        }
#pragma unroll
        for (int mi = 0; mi < 8; ++mi)
            af[mi] = __builtin_bit_cast(bf16x8,
                *reinterpret_cast<const u16x8*>(&Lb[aoff + mi * 512]));
        bfr[0] = __builtin_bit_cast(bf16x8,
            *reinterpret_cast<const u16x8*>(&Lb[boff]));
        bfr[1] = __builtin_bit_cast(bf16x8,
            *reinterpret_cast<const u16x8*>(&Lb[boff + 512]));
        __builtin_amdgcn_s_setprio(1);
#pragma unroll
        for (int mi = 0; mi < 8; ++mi) {
            acc[mi][0] = __builtin_amdgcn_mfma_f32_16x16x32_bf16(
                af[mi], bfr[0], acc[mi][0], 0, 0, 0);
            acc[mi][1] = __builtin_amdgcn_mfma_f32_16x16x32_bf16(
                af[mi], bfr[1], acc[mi][1], 0, 0, 0);
        }
        __builtin_amdgcn_s_setprio(0);
        // ---- phase 2: stage B(t+2); read B n2,n3; MFMA other half ----
        if (pf < NT) {
            async_cp16(Bsrc + (size_t)pf * 32, &lds[bp + 8192] + t * 8);
            async_cp16(Bsrc + Bstep + (size_t)pf * 32, &lds[bp + 8192] + t * 8 + 4096);
        }
        bfr[2] = __builtin_bit_cast(bf16x8,
            *reinterpret_cast<const u16x8*>(&Lb[boff + 1024]));
        bfr[3] = __builtin_bit_cast(bf16x8,
            *reinterpret_cast<const u16x8*>(&Lb[boff + 1536]));
        __builtin_amdgcn_s_setprio(1);
#pragma unroll
        for (int mi = 0; mi < 8; ++mi) {
            acc[mi][2] = __builtin_amdgcn_mfma_f32_16x16x32_bf16(
                af[mi], bfr[2], acc[mi][2], 0, 0, 0);
            acc[mi][3] = __builtin_amdgcn_mfma_f32_16x16x32_bf16(
                af[mi], bfr[3], acc[mi][3], 0, 0, 0);
        }
        __builtin_amdgcn_s_setprio(0);
        // ---- boundary: counted vmcnt (tile t+1 visible; t+2 in flight) ----
        if (tt + 1 < NT) {
            if (pf < NT)
                asm volatile("s_waitcnt vmcnt(4)\n\ts_barrier" ::: "memory");
            else
                asm volatile("s_waitcnt vmcnt(0)\n\ts_barrier" ::: "memory");
        }
    }

#pragma unroll
    for (int mi = 0; mi < 8; ++mi) {
        const int gr0 = m0 + wm * 128 + mi * 16 + quad * 4;
#pragma unroll
        for (int ni = 0; ni < 4; ++ni) {
            const int gc = n0 + wn * 64 + ni * 16 + l16;
            if (MODE == 2) {
                const float bv = bias[gc];
                if (gc < 2048) {
#pragma unroll
                    for (int r = 0; r < 4; ++r)
                        ((unsigned short*)Cv)[(size_t)(gr0 + r) * 2048 + gc] =
                            f2b(acc[mi][ni][r] + bv);
                } else {
                    u16x4 pk;
#pragma unroll
                    for (int r = 0; r < 4; ++r) pk[r] = f2b(acc[mi][ni][r] + bv);
                    const int bb = gr0 >> 11, s0 = gr0 & 2047;
                    *reinterpret_cast<u16x4*>(
                        &((unsigned short*)Cv2)[((size_t)bb * 1024 + (gc - 2048)) * 2048 + s0]) = pk;
                }
            } else if (MODE == 5) {
                unsigned short* base = (blockIdx.z < 2)
                    ? (unsigned short*)Cv  + (size_t)blockIdx.z * 4096 * N
                    : (unsigned short*)Cv2 + (size_t)(blockIdx.z - 2) * 4096 * N;
#pragma unroll
                for (int r = 0; r < 4; ++r)
                    base[(size_t)(gr0 + r) * N + gc] = f2b(acc[mi][ni][r]);
            } else {
                const float bv = bias[gc];
#pragma unroll
                for (int r = 0; r < 4; ++r) {
                    float v = acc[mi][ni][r] + bv;
                    if (RELU) v = fmaxf(v, 0.f);
                    ((unsigned short*)Cv)[(size_t)(gr0 + r) * N + gc] = f2b(v);
                }
            }
        }
    }
}

// ---------------------------------------------------------------------------
// Flash attention, r13 (kept — at its multi-pipe floor, 0 conflicts).
// K pre-scaled by log2(e)/8 -> p = exp2(s). qkb: [4096][2048]; vbT V^T.
// Grid (16, 32): 128 q/block, 4 waves x 32 q. DMA staging into TRIPLE-
// buffered swizzled LDS, counted vmcnt(4), one barrier per tile.
// S^T via mfma(A=K, B=Q); PV A-frag via permlane swaps; l via ones-MFMA.
// ---------------------------------------------------------------------------
__global__ __launch_bounds__(256, 2) void attn_kernel(
    const unsigned short* __restrict__ qkb, const unsigned short* __restrict__ vbT,
    unsigned short* __restrict__ ao)
{
    __shared__ unsigned short lds[3 * 8192];   // [buf][K 4096 | V 4096] elems
    const int t = threadIdx.x;
    const int lane = t & 63;
    const int quad = lane >> 4, l16 = lane & 15;
    const int wave = t >> 6;
    const int bh = blockIdx.y;
    const int b = bh >> 4, h = bh & 15;
    const int q0 = blockIdx.x * 128 + wave * 32;
    const size_t qk_base = (size_t)b * 2048 * 2048;
    const size_t vt_base = (size_t)b * 1024 * 2048 + (size_t)h * 64 * 2048;

    // Q as B-operand: lane holds Q[q=l16 (+16m)][d=quad*8+j (+32kk)]
    bf16x8 qf[2][2];
#pragma unroll
    for (int m = 0; m < 2; ++m)
#pragma unroll
        for (int kk = 0; kk < 2; ++kk)
            qf[m][kk] = __builtin_bit_cast(bf16x8, *reinterpret_cast<const u16x8*>(
                &qkb[qk_base + (size_t)(q0 + m * 16 + l16) * 2048 + h * 64 + kk * 32 + quad * 8]));

    // ones fragment (bf16 1.0 = 0x3F80) for l = P @ 1
    u16x8 ones_u;
#pragma unroll
    for (int j = 0; j < 8; ++j) ones_u[j] = 0x3F80;
    const bf16x8 onesf = __builtin_bit_cast(bf16x8, ones_u);

    f32x4 o_acc[2][4], l_frag[2];
#pragma unroll
    for (int m = 0; m < 2; ++m) {
        l_frag[m] = {0.f, 0.f, 0.f, 0.f};
#pragma unroll
        for (int nf = 0; nf < 4; ++nf) o_acc[m][nf] = {0.f, 0.f, 0.f, 0.f};
    }

    // staging: chunk c (c0=t, c1=t+256): row=c>>3, src colblk=(c&7)^(row&7)
    const int c0 = t, c1 = t + 256;
    const int r0 = c0 >> 3, r1 = c1 >> 3;
    const int scb0 = (c0 & 7) ^ (r0 & 7), scb1 = (c1 & 7) ^ (r1 & 7);
    const unsigned short* kS0 = &qkb[qk_base + (size_t)r0 * 2048 + 1024 + h * 64 + scb0 * 8];
    const unsigned short* kS1 = &qkb[qk_base + (size_t)r1 * 2048 + 1024 + h * 64 + scb1 * 8];
    const unsigned short* vS0 = &vbT[vt_base + (size_t)r0 * 2048 + scb0 * 8];
    const unsigned short* vS1 = &vbT[vt_base + (size_t)r1 * 2048 + scb1 * 8];

    // fragment read base: row l16, swizzled colblk (quad ^ (l16&7))
    const int off0 = l16 * 64 + ((quad ^ (l16 & 7)) * 8);

#define STAGE(tile, buf)                                                      \
    {                                                                         \
        const size_t ko = (size_t)(tile) * 64 * 2048;                         \
        const int vo = (tile) * 64;                                           \
        async_cp16(kS0 + ko, &lds[(buf) * 8192 + c0 * 8]);                    \
        async_cp16(kS1 + ko, &lds[(buf) * 8192 + c1 * 8]);                    \
        async_cp16(vS0 + vo, &lds[(buf) * 8192 + 4096 + c0 * 8]);             \
        async_cp16(vS1 + vo, &lds[(buf) * 8192 + 4096 + c1 * 8]);             \
    }

    // prologue: tile0 -> buf0, tile1 -> buf1; wait tile0 (4 still in flight)
    STAGE(0, 0);
    STAGE(1, 1);
    asm volatile("s_waitcnt vmcnt(4)\n\ts_barrier" ::: "memory");

    for (int tt = 0; tt < 32; ++tt) {
        const int buf = tt - (tt / 3) * 3;
        const int pf = tt + 2;
        if (pf < 32) {
            const int bp = pf - (pf / 3) * 3;
            STAGE(pf, bp);
        }
        const unsigned short* LK = &lds[buf * 8192];
        const unsigned short* LV = LK + 4096;

        // S^T for the four 16-key fragments of this 64-key tile
        unsigned d0[2][4], d1[2][4];   // [m][kf]
#pragma unroll
        for (int kf = 0; kf < 4; ++kf) {
            bf16x8 kfr0 = __builtin_bit_cast(bf16x8,
                *reinterpret_cast<const u16x8*>(&LK[off0 + kf * 1024]));
            bf16x8 kfr1 = __builtin_bit_cast(bf16x8,
                *reinterpret_cast<const u16x8*>(&LK[(off0 ^ 32) + kf * 1024]));
#pragma unroll
            for (int m = 0; m < 2; ++m) {
                f32x4 s = {0.f, 0.f, 0.f, 0.f};
                s = __builtin_amdgcn_mfma_f32_16x16x32_bf16(kfr0, qf[m][0], s, 0, 0, 0);
                s = __builtin_amdgcn_mfma_f32_16x16x32_bf16(kfr1, qf[m][1], s, 0, 0, 0);
                d0[m][kf] = (unsigned)f2b(exp2f(s[0])) |
                            ((unsigned)f2b(exp2f(s[1])) << 16);
                d1[m][kf] = (unsigned)f2b(exp2f(s[2])) |
                            ((unsigned)f2b(exp2f(s[3])) << 16);
            }
        }
#pragma unroll
        for (int kh = 0; kh < 2; ++kh) {
            bf16x8 pfr[2];
#pragma unroll
            for (int m = 0; m < 2; ++m) {
                unsigned x0 = d0[m][kh * 2], y0 = d0[m][kh * 2 + 1];
                unsigned x1 = d1[m][kh * 2], y1 = d1[m][kh * 2 + 1];
                asm("v_permlane32_swap_b32 %0, %1\n\t"
                    "v_permlane16_swap_b32 %0, %1"
                    : "+v"(x0), "+v"(y0));
                asm("v_permlane32_swap_b32 %0, %1\n\t"
                    "v_permlane16_swap_b32 %0, %1"
                    : "+v"(x1), "+v"(y1));
                u32x4 pw = {x0, x1, y0, y1};   // W0,W1,W2,W3
                pfr[m] = __builtin_bit_cast(bf16x8, pw);
                l_frag[m] = __builtin_amdgcn_mfma_f32_16x16x32_bf16(
                    pfr[m], onesf, l_frag[m], 0, 0, 0);
            }
            __builtin_amdgcn_s_setprio(1);
#pragma unroll
            for (int nf = 0; nf < 4; ++nf) {
                bf16x8 vfr = __builtin_bit_cast(bf16x8,
                    *reinterpret_cast<const u16x8*>(&LV[(off0 ^ (kh * 32)) + nf * 1024]));
#pragma unroll
                for (int m = 0; m < 2; ++m)
                    o_acc[m][nf] = __builtin_amdgcn_mfma_f32_16x16x32_bf16(
                        pfr[m], vfr, o_acc[m][nf], 0, 0, 0);
            }
            __builtin_amdgcn_s_setprio(0);
        }
        // boundary: tile tt+1 visible after barrier; tile tt+2 still in flight
        if (tt + 1 < 32) {
            if (pf < 32)
                asm volatile("s_waitcnt vmcnt(4)\n\ts_barrier" ::: "memory");
            else
                asm volatile("s_waitcnt vmcnt(0)\n\ts_barrier" ::: "memory");
        }
    }
#undef STAGE

    // store: o_acc rows q = q0 + m*16 + quad*4 + r; l_frag rows align.
#pragma unroll
    for (int m = 0; m < 2; ++m) {
#pragma unroll
        for (int r = 0; r < 4; ++r) {
            const float inv = 1.0f / l_frag[m][r];
            const int row = q0 + m * 16 + quad * 4 + r;
#pragma unroll
            for (int nf = 0; nf < 4; ++nf)
                ao[(size_t)b * 2048 * 1024 + (size_t)row * 1024 + h * 64 + nf * 16 + l16] =
                    f2b(o_acc[m][nf][r] * inv);
        }
    }
}

// ---------------------------------------------------------------------------
extern "C" void kernel_launch(void* const* d_in, const int* in_sizes, int n_in,
                              void* d_out, int out_size, void* d_ws, size_t ws_size,
                              hipStream_t stream)
{
    const float* x   = (const float*)d_in[0];
    const float* wq  = (const float*)d_in[1];
    const float* bq  = (const float*)d_in[2];
    const float* wk  = (const float*)d_in[3];
    const float* bk  = (const float*)d_in[4];
    const float* wv  = (const float*)d_in[5];
    const float* bv  = (const float*)d_in[6];
    const float* wo  = (const float*)d_in[7];
    const float* bo  = (const float*)d_in[8];
    const float* w1  = (const float*)d_in[9];
    const float* b1  = (const float*)d_in[10];
    const float* w2  = (const float*)d_in[11];
    const float* b2  = (const float*)d_in[12];
    const float* g1  = (const float*)d_in[13];
    const float* be1 = (const float*)d_in[14];
    const float* g2  = (const float*)d_in[15];
    const float* be2 = (const float*)d_in[16];
    float* out = (float*)d_out;
    char*  ws  = (char*)d_ws;

    const int M = 4096, D = 1024, DFF = 4096;
    const size_t MB = 1 << 20;

    unsigned short* wqkvT = (unsigned short*)(ws + 0 * MB);   // [3072][1024] 6MB
    unsigned short* woT   = (unsigned short*)(ws + 6 * MB);   // 2MB
    unsigned short* w1T   = (unsigned short*)(ws + 8 * MB);   // 8MB
    unsigned short* w2T   = (unsigned short*)(ws + 16 * MB);  // 8MB
    unsigned short* ln    = (unsigned short*)(ws + 24 * MB);  // 8MB
    unsigned short* qkb   = (unsigned short*)(ws + 32 * MB);  // 16MB
    unsigned short* vbT   = (unsigned short*)(ws + 48 * MB);  // 8MB
    unsigned short* ao    = (unsigned short*)(ws + 56 * MB);  // 8MB
    unsigned short* ff1   = (unsigned short*)(ws + 32 * MB);  // 32MB (reuse)
    float*          x2    = (float*)(ws + 64 * MB);           // 16MB
    float*          bqkv  = (float*)(ws + 80 * MB);           // 12KB (pre-partials)
    unsigned short* pHi   = (unsigned short*)(ws + 80 * MB);  // slices 0,1 (16MB)
    unsigned short* pOlo  = (unsigned short*)(ws + 32 * MB);  // O-proj slices 2,3
    unsigned short* pFlo  = (unsigned short*)(ws + 0 * MB);   // FF2 slices 2,3

    // --- weight prep + bias concat + LN1 (one launch) ---
    prep_all_k<<<16396, 256, 0, stream>>>(wq, wk, wv, wo, w1, w2,
                                          wqkvT, woT, w1T, w2T,
                                          bq, bk, bv, bqkv,
                                          x, g1, be1, ln);
    // --- fused QKV projection: QK' -> qkb, V -> vbT (V^T) ---
    gemm256<2, 0><<<dim3(12, 16), 512, 0, stream>>>(
        ln, D, wqkvT, D, bqkv, qkb, vbT, 3072, D);
    // --- attention ---
    attn_kernel<<<dim3(16, 32), 256, 0, stream>>>(qkb, vbT, ao);
    // --- O projection split-K4 bf16 partials; reduce + residual + LN2 ---
    gemm256<5, 0><<<dim3(4, 16, 4), 512, 0, stream>>>(
        ao, D, woT, D, nullptr, pHi, pOlo, 1024, 256);
    reduce_ln_kernel<<<M, 256, 0, stream>>>(pHi, pOlo, bo, x, g2, be2, x2, ln);
    // --- FFN ---
    gemm256<0, 1><<<dim3(16, 16), 512, 0, stream>>>(
        ln, D, w1T, D, b1, ff1, nullptr, DFF, D);
    gemm256<5, 0><<<dim3(4, 16, 4), 512, 0, stream>>>(
        ff1, DFF, w2T, DFF, nullptr, pHi, pFlo, 1024, 1024);
    reduce_out4_k<<<4096, 256, 0, stream>>>(pHi, pFlo, b2, x2, out);
}

// Round 11
// 327.853 us; speedup vs baseline: 1.0630x; 1.0496x over previous
//
#include <hip/hip_runtime.h>

// ---------------------------------------------------------------------------
// EncoderLayer, MI355X gfx950. fp32 I/O, bf16 MFMA internally.
// r19 = r18 (344.1us best) + ONE change: attn exp2f -> raw v_exp_f32 inline
//      asm. Theory: VALU budget shows ~750 VALU-issues/wave-tile vs ~80
//      accounted; exp2f without fast-math lowers to the guarded
//      __ocml_exp2_f32 wrapper (~6-10 ops) instead of the single trans op.
//      16 exp2/tile x 32 tiles sits on attn's critical chain.
// Session summary (validated): gemm256 256^2 BK=32 triple-buffer + counted
//   vmcnt(4) (r12); attn DMA staging + swizzle + counted vmcnt (r13);
//   T1 XCD swizzle + prep merge (r16). Falsified: BK=64 drain (r14),
//   full-K 128^2 (r15), 8-phase (r17).
// MFMA 16x16x32 bf16 layouts (m89/m91 verified):
//   A: lane holds A[m=lane&15][k=quad*8+j]; B: Bt[n=lane&15][k=quad*8+j]
//   C/D: reg r -> row=quad*4+r, col=lane&15
// Workspace (MB): 0-6 wqkvT | 6-8 woT | 8-16 w1T | 16-24 w2T | 24-32 ln |
//   32-48 qkb | 48-56 vbT | 56-64 ao | 64-80 x2 | 80-96 partials hi
// ---------------------------------------------------------------------------

typedef __attribute__((ext_vector_type(8))) unsigned short u16x8;
typedef __attribute__((ext_vector_type(4))) unsigned short u16x4;
typedef __attribute__((ext_vector_type(8))) __bf16 bf16x8;
typedef __attribute__((ext_vector_type(4))) float f32x4;
typedef __attribute__((ext_vector_type(4))) unsigned int u32x4;

#define C_SCALE 0.1803368801111f   // log2(e)/8 — folded into wk/bk

static __device__ __forceinline__ unsigned short f2b(float f) {
    return __builtin_bit_cast(unsigned short, (__bf16)f);
}
static __device__ __forceinline__ float b2f(unsigned short h) {
    unsigned u = ((unsigned)h) << 16;
    float f;
    __builtin_memcpy(&f, &u, 4);
    return f;
}
// raw v_exp_f32 (D = 2^S0), bypassing the OCML guarded wrapper
static __device__ __forceinline__ float fast_exp2(float x) {
    float r;
    asm("v_exp_f32 %0, %1" : "=v"(r) : "v"(x));
    return r;
}

static __device__ __forceinline__ void async_cp16(
    const unsigned short* g, unsigned short* l)
{
    __builtin_amdgcn_global_load_lds(
        (const __attribute__((address_space(1))) unsigned int*)g,
        (__attribute__((address_space(3))) unsigned int*)l,
        16, 0, 0);
}

// ---------------------------------------------------------------------------
// Merged prep: blocks [0,12288) six weight transposes (fp32->bf16, [R][C]->
// [C][R]); [12288,12300) bias concat; [12300,16396) LayerNorm1 rows.
// Branch is blockIdx-uniform -> per-branch __syncthreads is legal.
// ---------------------------------------------------------------------------
__global__ __launch_bounds__(256) void prep_all_k(
    const float* __restrict__ wq, const float* __restrict__ wk,
    const float* __restrict__ wv, const float* __restrict__ wo,
    const float* __restrict__ w1, const float* __restrict__ w2,
    unsigned short* __restrict__ wqkvT, unsigned short* __restrict__ woT,
    unsigned short* __restrict__ w1T, unsigned short* __restrict__ w2T,
    const float* __restrict__ bq, const float* __restrict__ bk,
    const float* __restrict__ bv, float* __restrict__ bqkv,
    const float* __restrict__ x, const float* __restrict__ g1,
    const float* __restrict__ be1, unsigned short* __restrict__ lnout)
{
    __shared__ unsigned short tile[32][33];
    __shared__ float sb[4], ssb[4];
    const int ti = blockIdx.x;

    if (ti < 12288) {                       // ---- transposes ----
        const float* in;
        unsigned short* out;
        int R, C, bi, bj;
        float sc = 1.0f;
        if (ti < 4096) {
            R = 1024; C = 1024;
            bi = (ti & 1023) >> 5; bj = ti & 31;
            int z = ti >> 10;
            in = (z == 0) ? wq : (z == 1) ? wk : (z == 2) ? wv : wo;
            out = (z < 3) ? wqkvT + (size_t)z * 1024 * 1024 : woT;
            if (z == 1) sc = C_SCALE;
        } else if (ti < 8192) {
            R = 1024; C = 4096;
            int l = ti - 4096;
            bi = l >> 7; bj = l & 127;
            in = w1; out = w1T;
        } else {
            R = 4096; C = 1024;
            int l = ti - 8192;
            bi = l >> 5; bj = l & 31;
            in = w2; out = w2T;
        }
        const int tx = threadIdx.x & 31, ty = threadIdx.x >> 5;
#pragma unroll
        for (int rr = 0; rr < 4; ++rr) {
            int r = ty + rr * 8;
            tile[r][tx] = f2b(in[(size_t)(bi * 32 + r) * C + bj * 32 + tx] * sc);
        }
        __syncthreads();
#pragma unroll
        for (int rr = 0; rr < 4; ++rr) {
            int r = ty + rr * 8;
            out[(size_t)(bj * 32 + r) * R + bi * 32 + tx] = tile[tx][r];
        }
        return;
    }
    if (ti < 12300) {                       // ---- bias concat ----
        int t = (ti - 12288) * 256 + threadIdx.x;
        float v = (t < 1024) ? bq[t]
                : ((t < 2048) ? bk[t - 1024] * C_SCALE : bv[t - 2048]);
        bqkv[t] = v;
        return;
    }
    // ---- LayerNorm1 ----
    const int row = ti - 12300;
    const int t = threadIdx.x;
    const float* xr = x + (size_t)row * 1024;
    float4 v4 = *reinterpret_cast<const float4*>(&xr[t * 4]);
    float f[4] = {v4.x, v4.y, v4.z, v4.w};
    float s = f[0] + f[1] + f[2] + f[3];
    float ss = f[0] * f[0] + f[1] * f[1] + f[2] * f[2] + f[3] * f[3];
#pragma unroll
    for (int d = 1; d < 64; d <<= 1) {
        s += __shfl_xor(s, d);
        ss += __shfl_xor(ss, d);
    }
    const int wave = t >> 6;
    if ((t & 63) == 0) { sb[wave] = s; ssb[wave] = ss; }
    __syncthreads();
    s = sb[0] + sb[1] + sb[2] + sb[3];
    ss = ssb[0] + ssb[1] + ssb[2] + ssb[3];
    const float mu = s * (1.0f / 1024.0f);
    const float var = ss * (1.0f / 1024.0f) - mu * mu;
    const float rs = rsqrtf(var + 1e-5f);
    u16x4 r4;
#pragma unroll
    for (int j = 0; j < 4; ++j)
        r4[j] = f2b((f[j] - mu) * rs * g1[t * 4 + j] + be1[t * 4 + j]);
    *reinterpret_cast<u16x4*>(&lnout[(size_t)row * 1024 + t * 4]) = r4;
}

// ---------------------------------------------------------------------------
// Fused: x2 = sum(4 bf16 partials) + bias + x;  ln = LayerNorm(x2; g, be)
// ---------------------------------------------------------------------------
__global__ __launch_bounds__(256) void reduce_ln_kernel(
    const unsigned short* __restrict__ pa, const unsigned short* __restrict__ pb,
    const float* __restrict__ bias, const float* __restrict__ x,
    const float* __restrict__ g, const float* __restrict__ be,
    float* __restrict__ x2, unsigned short* __restrict__ o)
{
    const int row = blockIdx.x;
    const int t = threadIdx.x;
    const size_t base = (size_t)row * 1024 + t * 4;
    float4 x4 = *reinterpret_cast<const float4*>(&x[base]);
    float4 bb = *reinterpret_cast<const float4*>(&bias[t * 4]);
    float f[4] = {x4.x + bb.x, x4.y + bb.y, x4.z + bb.z, x4.w + bb.w};
#pragma unroll
    for (int z = 0; z < 2; ++z) {
        u16x4 va = *reinterpret_cast<const u16x4*>(&pa[(size_t)z * 4096 * 1024 + base]);
        u16x4 vb = *reinterpret_cast<const u16x4*>(&pb[(size_t)z * 4096 * 1024 + base]);
#pragma unroll
        for (int j = 0; j < 4; ++j) f[j] += b2f(va[j]) + b2f(vb[j]);
    }
    *reinterpret_cast<float4*>(&x2[base]) = {f[0], f[1], f[2], f[3]};
    float s = f[0] + f[1] + f[2] + f[3];
    float ss = f[0] * f[0] + f[1] * f[1] + f[2] * f[2] + f[3] * f[3];
#pragma unroll
    for (int d = 1; d < 64; d <<= 1) {
        s += __shfl_xor(s, d);
        ss += __shfl_xor(ss, d);
    }
    __shared__ float sb[4], ssb[4];
    const int wave = t >> 6;
    if ((t & 63) == 0) { sb[wave] = s; ssb[wave] = ss; }
    __syncthreads();
    s = sb[0] + sb[1] + sb[2] + sb[3];
    ss = ssb[0] + ssb[1] + ssb[2] + ssb[3];
    const float mu = s * (1.0f / 1024.0f);
    const float var = ss * (1.0f / 1024.0f) - mu * mu;
    const float rs = rsqrtf(var + 1e-5f);
    u16x4 r4;
#pragma unroll
    for (int j = 0; j < 4; ++j)
        r4[j] = f2b((f[j] - mu) * rs * g[t * 4 + j] + be[t * 4 + j]);
    *reinterpret_cast<u16x4*>(&o[base]) = r4;
}

// ---------------------------------------------------------------------------
// Fused final: out = sum(4 bf16 partials) + bias + x2
// ---------------------------------------------------------------------------
__global__ __launch_bounds__(256) void reduce_out4_k(
    const unsigned short* __restrict__ pa, const unsigned short* __restrict__ pb,
    const float* __restrict__ bias, const float* __restrict__ x2,
    float* __restrict__ out)
{
    const size_t i4 = ((size_t)blockIdx.x * 256 + threadIdx.x) * 4;
    float4 x4 = *reinterpret_cast<const float4*>(&x2[i4]);
    float4 bb = *reinterpret_cast<const float4*>(&bias[i4 & 1023]);
    float a0 = x4.x + bb.x, a1 = x4.y + bb.y, a2 = x4.z + bb.z, a3 = x4.w + bb.w;
#pragma unroll
    for (int z = 0; z < 2; ++z) {
        u16x4 va = *reinterpret_cast<const u16x4*>(&pa[(size_t)z * 4096 * 1024 + i4]);
        u16x4 vb = *reinterpret_cast<const u16x4*>(&pb[(size_t)z * 4096 * 1024 + i4]);
        a0 += b2f(va[0]) + b2f(vb[0]);
        a1 += b2f(va[1]) + b2f(vb[1]);
        a2 += b2f(va[2]) + b2f(vb[2]);
        a3 += b2f(va[3]) + b2f(vb[3]);
    }
    *reinterpret_cast<float4*>(&out[i4]) = {a0, a1, a2, a3};
}

// ---------------------------------------------------------------------------
// gemm256 (r13 + T1): C[M][.] = A[M][lda] @ Bt[.][ldb]^T (+bias)(+ReLU)
// BM=BN=256, BK=32, 512 threads (8 waves: wm=w>>2, wn=w&3), per-wave 128x64.
// Triple-buffered LDS (96KB), counted vmcnt(4) boundary + ONE barrier per
// K-tile. T2 swizzle both sides. T1: XCD-bijective blockIdx swizzle
// (requires gridDim.x*gridDim.y % 8 == 0 — true for all call sites).
// MODE 0: bf16 row-major (+ReLU); 2: fused QKV epilogue; 5: partial slices.
// ---------------------------------------------------------------------------
template<int MODE, int RELU>
__global__ __launch_bounds__(512, 1) void gemm256(
    const unsigned short* __restrict__ A, int lda,
    const unsigned short* __restrict__ Bt, int ldb,
    const float* __restrict__ bias,
    void* __restrict__ Cv, void* __restrict__ Cv2, int N, int Kloop)
{
    __shared__ unsigned short lds[3 * 16384];   // 96 KB
    const int t = threadIdx.x;
    const int wave = t >> 6, lane = t & 63;
    const int quad = lane >> 4, l16 = lane & 15;
    const int wm = wave >> 2, wn = wave & 3;
    // T1: XCD-chunked bijective remap of the xy block index
    const int nwg = gridDim.x * gridDim.y;
    const int id = blockIdx.y * gridDim.x + blockIdx.x;
    const int sw = (id & 7) * (nwg >> 3) + (id >> 3);
    const int m0 = (sw / gridDim.x) * 256;
    const int n0 = (sw % gridDim.x) * 256;
    const int k0 = blockIdx.z * Kloop;
    const int NT = Kloop >> 5;

    // staging: thread t covers row ph*128 + (t>>2), source colblk pre-swizzled
    const int sc_row = t >> 2;
    const int sc_cb  = (t & 3) ^ ((t >> 3) & 3);
    const unsigned short* Asrc = &A[(size_t)(m0 + sc_row) * lda + k0 + sc_cb * 8];
    const unsigned short* Bsrc = &Bt[(size_t)(n0 + sc_row) * ldb + k0 + sc_cb * 8];
    const size_t Astep = (size_t)128 * lda;
    const size_t Bstep = (size_t)128 * ldb;
    unsigned short* dstA = &lds[t * 8];
    unsigned short* dstB = &lds[8192 + t * 8];

    // fragment read offsets (swizzled colblk, constant per lane)
    const int cb = quad ^ ((l16 >> 1) & 3);
    const int aoff = (wm * 128 + l16) * 32 + cb * 8;          // + mi*512
    const int boff = 8192 + (wn * 64 + l16) * 32 + cb * 8;    // + ni*512

    f32x4 acc[8][4];
#pragma unroll
    for (int mi = 0; mi < 8; ++mi)
#pragma unroll
        for (int ni = 0; ni < 4; ++ni) acc[mi][ni] = {0.f, 0.f, 0.f, 0.f};

    // prologue: stage tile0 -> buf0, tile1 -> buf1
    async_cp16(Asrc, dstA);
    async_cp16(Asrc + Astep, dstA + 4096);
    async_cp16(Bsrc, dstB);
    async_cp16(Bsrc + Bstep, dstB + 4096);
    if (NT > 1) {
        async_cp16(Asrc + 32, dstA + 16384);
        async_cp16(Asrc + Astep + 32, dstA + 16384 + 4096);
        async_cp16(Bsrc + 32, dstB + 16384);
        async_cp16(Bsrc + Bstep + 32, dstB + 16384 + 4096);
        asm volatile("s_waitcnt vmcnt(4)\n\ts_barrier" ::: "memory");
    } else {
        asm volatile("s_waitcnt vmcnt(0)\n\ts_barrier" ::: "memory");
    }

    for (int tt = 0; tt < NT; ++tt) {
        const int b = tt - (tt / 3) * 3;
        const unsigned short* Lb = &lds[b * 16384];
        const int pf = tt + 2;
        const int bp = (pf < NT) ? (pf - (pf / 3) * 3) * 16384 : 0;
        bf16x8 af[8], bfr[4];
        // ---- phase 1: stage A(t+2); read A frags + B n0,n1; MFMA half ----
        if (pf < NT) {
            async_cp16(Asrc + (size_t)pf * 32, &lds[bp] + t * 8);
            async_cp16(Asrc + Astep + (size_t)pf * 32, &lds[bp] + t * 8 + 4096);
        }
#pragma unroll
        for (int mi = 0; mi < 8; ++mi)
            af[mi] = __builtin_bit_cast(bf16x8,
                *reinterpret_cast<const u16x8*>(&Lb[aoff + mi * 512]));
        bfr[0] = __builtin_bit_cast(bf16x8,
            *reinterpret_cast<const u16x8*>(&Lb[boff]));
        bfr[1] = __builtin_bit_cast(bf16x8,
            *reinterpret_cast<const u16x8*>(&Lb[boff + 512]));
        __builtin_amdgcn_s_setprio(1);
#pragma unroll
        for (int mi = 0; mi < 8; ++mi) {
            acc[mi][0] = __builtin_amdgcn_mfma_f32_16x16x32_bf16(
                af[mi], bfr[0], acc[mi][0], 0, 0, 0);
            acc[mi][1] = __builtin_amdgcn_mfma_f32_16x16x32_bf16(
                af[mi], bfr[1], acc[mi][1], 0, 0, 0);
        }
        __builtin_amdgcn_s_setprio(0);
        // ---- phase 2: stage B(t+2); read B n2,n3; MFMA other half ----
        if (pf < NT) {
            async_cp16(Bsrc + (size_t)pf * 32, &lds[bp + 8192] + t * 8);
            async_cp16(Bsrc + Bstep + (size_t)pf * 32, &lds[bp + 8192] + t * 8 + 4096);
        }
        bfr[2] = __builtin_bit_cast(bf16x8,
            *reinterpret_cast<const u16x8*>(&Lb[boff + 1024]));
        bfr[3] = __builtin_bit_cast(bf16x8,
            *reinterpret_cast<const u16x8*>(&Lb[boff + 1536]));
        __builtin_amdgcn_s_setprio(1);
#pragma unroll
        for (int mi = 0; mi < 8; ++mi) {
            acc[mi][2] = __builtin_amdgcn_mfma_f32_16x16x32_bf16(
                af[mi], bfr[2], acc[mi][2], 0, 0, 0);
            acc[mi][3] = __builtin_amdgcn_mfma_f32_16x16x32_bf16(
                af[mi], bfr[3], acc[mi][3], 0, 0, 0);
        }
        __builtin_amdgcn_s_setprio(0);
        // ---- boundary: counted vmcnt (tile t+1 visible; t+2 in flight) ----
        if (tt + 1 < NT) {
            if (pf < NT)
                asm volatile("s_waitcnt vmcnt(4)\n\ts_barrier" ::: "memory");
            else
                asm volatile("s_waitcnt vmcnt(0)\n\ts_barrier" ::: "memory");
        }
    }

#pragma unroll
    for (int mi = 0; mi < 8; ++mi) {
        const int gr0 = m0 + wm * 128 + mi * 16 + quad * 4;
#pragma unroll
        for (int ni = 0; ni < 4; ++ni) {
            const int gc = n0 + wn * 64 + ni * 16 + l16;
            if (MODE == 2) {
                const float bv = bias[gc];
                if (gc < 2048) {
#pragma unroll
                    for (int r = 0; r < 4; ++r)
                        ((unsigned short*)Cv)[(size_t)(gr0 + r) * 2048 + gc] =
                            f2b(acc[mi][ni][r] + bv);
                } else {
                    u16x4 pk;
#pragma unroll
                    for (int r = 0; r < 4; ++r) pk[r] = f2b(acc[mi][ni][r] + bv);
                    const int bb = gr0 >> 11, s0 = gr0 & 2047;
                    *reinterpret_cast<u16x4*>(
                        &((unsigned short*)Cv2)[((size_t)bb * 1024 + (gc - 2048)) * 2048 + s0]) = pk;
                }
            } else if (MODE == 5) {
                unsigned short* base = (blockIdx.z < 2)
                    ? (unsigned short*)Cv  + (size_t)blockIdx.z * 4096 * N
                    : (unsigned short*)Cv2 + (size_t)(blockIdx.z - 2) * 4096 * N;
#pragma unroll
                for (int r = 0; r < 4; ++r)
                    base[(size_t)(gr0 + r) * N + gc] = f2b(acc[mi][ni][r]);
            } else {
                const float bv = bias[gc];
#pragma unroll
                for (int r = 0; r < 4; ++r) {
                    float v = acc[mi][ni][r] + bv;
                    if (RELU) v = fmaxf(v, 0.f);
                    ((unsigned short*)Cv)[(size_t)(gr0 + r) * N + gc] = f2b(v);
                }
            }
        }
    }
}

// ---------------------------------------------------------------------------
// Flash attention (r13 structure + raw v_exp_f32). K pre-scaled by log2(e)/8
// -> p = 2^s via fast_exp2. qkb: [4096][2048]; vbT V^T. Grid (16, 32):
// 128 q/block, 4 waves x 32 q. DMA staging into TRIPLE-buffered swizzled
// LDS, counted vmcnt(4), one barrier per tile. S^T via mfma(A=K, B=Q);
// PV A-frag via permlane swaps; l via ones-MFMA.
// ---------------------------------------------------------------------------
__global__ __launch_bounds__(256, 2) void attn_kernel(
    const unsigned short* __restrict__ qkb, const unsigned short* __restrict__ vbT,
    unsigned short* __restrict__ ao)
{
    __shared__ unsigned short lds[3 * 8192];   // [buf][K 4096 | V 4096] elems
    const int t = threadIdx.x;
    const int lane = t & 63;
    const int quad = lane >> 4, l16 = lane & 15;
    const int wave = t >> 6;
    const int bh = blockIdx.y;
    const int b = bh >> 4, h = bh & 15;
    const int q0 = blockIdx.x * 128 + wave * 32;
    const size_t qk_base = (size_t)b * 2048 * 2048;
    const size_t vt_base = (size_t)b * 1024 * 2048 + (size_t)h * 64 * 2048;

    // Q as B-operand: lane holds Q[q=l16 (+16m)][d=quad*8+j (+32kk)]
    bf16x8 qf[2][2];
#pragma unroll
    for (int m = 0; m < 2; ++m)
#pragma unroll
        for (int kk = 0; kk < 2; ++kk)
            qf[m][kk] = __builtin_bit_cast(bf16x8, *reinterpret_cast<const u16x8*>(
                &qkb[qk_base + (size_t)(q0 + m * 16 + l16) * 2048 + h * 64 + kk * 32 + quad * 8]));

    // ones fragment (bf16 1.0 = 0x3F80) for l = P @ 1
    u16x8 ones_u;
#pragma unroll
    for (int j = 0; j < 8; ++j) ones_u[j] = 0x3F80;
    const bf16x8 onesf = __builtin_bit_cast(bf16x8, ones_u);

    f32x4 o_acc[2][4], l_frag[2];
#pragma unroll
    for (int m = 0; m < 2; ++m) {
        l_frag[m] = {0.f, 0.f, 0.f, 0.f};
#pragma unroll
        for (int nf = 0; nf < 4; ++nf) o_acc[m][nf] = {0.f, 0.f, 0.f, 0.f};
    }

    // staging: chunk c (c0=t, c1=t+256): row=c>>3, src colblk=(c&7)^(row&7)
    const int c0 = t, c1 = t + 256;
    const int r0 = c0 >> 3, r1 = c1 >> 3;
    const int scb0 = (c0 & 7) ^ (r0 & 7), scb1 = (c1 & 7) ^ (r1 & 7);
    const unsigned short* kS0 = &qkb[qk_base + (size_t)r0 * 2048 + 1024 + h * 64 + scb0 * 8];
    const unsigned short* kS1 = &qkb[qk_base + (size_t)r1 * 2048 + 1024 + h * 64 + scb1 * 8];
    const unsigned short* vS0 = &vbT[vt_base + (size_t)r0 * 2048 + scb0 * 8];
    const unsigned short* vS1 = &vbT[vt_base + (size_t)r1 * 2048 + scb1 * 8];

    // fragment read base: row l16, swizzled colblk (quad ^ (l16&7))
    const int off0 = l16 * 64 + ((quad ^ (l16 & 7)) * 8);

#define STAGE(tile, buf)                                                      \
    {                                                                         \
        const size_t ko = (size_t)(tile) * 64 * 2048;                         \
        const int vo = (tile) * 64;                                           \
        async_cp16(kS0 + ko, &lds[(buf) * 8192 + c0 * 8]);                    \
        async_cp16(kS1 + ko, &lds[(buf) * 8192 + c1 * 8]);                    \
        async_cp16(vS0 + vo, &lds[(buf) * 8192 + 4096 + c0 * 8]);             \
        async_cp16(vS1 + vo, &lds[(buf) * 8192 + 4096 + c1 * 8]);             \
    }

    // prologue: tile0 -> buf0, tile1 -> buf1; wait tile0 (4 still in flight)
    STAGE(0, 0);
    STAGE(1, 1);
    asm volatile("s_waitcnt vmcnt(4)\n\ts_barrier" ::: "memory");

    for (int tt = 0; tt < 32; ++tt) {
        const int buf = tt - (tt / 3) * 3;
        const int pf = tt + 2;
        if (pf < 32) {
            const int bp = pf - (pf / 3) * 3;
            STAGE(pf, bp);
        }
        const unsigned short* LK = &lds[buf * 8192];
        const unsigned short* LV = LK + 4096;

        // S^T for the four 16-key fragments of this 64-key tile
        unsigned d0[2][4], d1[2][4];   // [m][kf]
#pragma unroll
        for (int kf = 0; kf < 4; ++kf) {
            bf16x8 kfr0 = __builtin_bit_cast(bf16x8,
                *reinterpret_cast<const u16x8*>(&LK[off0 + kf * 1024]));
            bf16x8 kfr1 = __builtin_bit_cast(bf16x8,
                *reinterpret_cast<const u16x8*>(&LK[(off0 ^ 32) + kf * 1024]));
#pragma unroll
            for (int m = 0; m < 2; ++m) {
                f32x4 s = {0.f, 0.f, 0.f, 0.f};
                s = __builtin_amdgcn_mfma_f32_16x16x32_bf16(kfr0, qf[m][0], s, 0, 0, 0);
                s = __builtin_amdgcn_mfma_f32_16x16x32_bf16(kfr1, qf[m][1], s, 0, 0, 0);
                d0[m][kf] = (unsigned)f2b(fast_exp2(s[0])) |
                            ((unsigned)f2b(fast_exp2(s[1])) << 16);
                d1[m][kf] = (unsigned)f2b(fast_exp2(s[2])) |
                            ((unsigned)f2b(fast_exp2(s[3])) << 16);
            }
        }
#pragma unroll
        for (int kh = 0; kh < 2; ++kh) {
            bf16x8 pfr[2];
#pragma unroll
            for (int m = 0; m < 2; ++m) {
                unsigned x0 = d0[m][kh * 2], y0 = d0[m][kh * 2 + 1];
                unsigned x1 = d1[m][kh * 2], y1 = d1[m][kh * 2 + 1];
                asm("v_permlane32_swap_b32 %0, %1\n\t"
                    "v_permlane16_swap_b32 %0, %1"
                    : "+v"(x0), "+v"(y0));
                asm("v_permlane32_swap_b32 %0, %1\n\t"
                    "v_permlane16_swap_b32 %0, %1"
                    : "+v"(x1), "+v"(y1));
                u32x4 pw = {x0, x1, y0, y1};   // W0,W1,W2,W3
                pfr[m] = __builtin_bit_cast(bf16x8, pw);
                l_frag[m] = __builtin_amdgcn_mfma_f32_16x16x32_bf16(
                    pfr[m], onesf, l_frag[m], 0, 0, 0);
            }
            __builtin_amdgcn_s_setprio(1);
#pragma unroll
            for (int nf = 0; nf < 4; ++nf) {
                bf16x8 vfr = __builtin_bit_cast(bf16x8,
                    *reinterpret_cast<const u16x8*>(&LV[(off0 ^ (kh * 32)) + nf * 1024]));
#pragma unroll
                for (int m = 0; m < 2; ++m)
                    o_acc[m][nf] = __builtin_amdgcn_mfma_f32_16x16x32_bf16(
                        pfr[m], vfr, o_acc[m][nf], 0, 0, 0);
            }
            __builtin_amdgcn_s_setprio(0);
        }
        // boundary: tile tt+1 visible after barrier; tile tt+2 still in flight
        if (tt + 1 < 32) {
            if (pf < 32)
                asm volatile("s_waitcnt vmcnt(4)\n\ts_barrier" ::: "memory");
            else
                asm volatile("s_waitcnt vmcnt(0)\n\ts_barrier" ::: "memory");
        }
    }
#undef STAGE

    // store: o_acc rows q = q0 + m*16 + quad*4 + r; l_frag rows align.
#pragma unroll
    for (int m = 0; m < 2; ++m) {
#pragma unroll
        for (int r = 0; r < 4; ++r) {
            const float inv = 1.0f / l_frag[m][r];
            const int row = q0 + m * 16 + quad * 4 + r;
#pragma unroll
            for (int nf = 0; nf < 4; ++nf)
                ao[(size_t)b * 2048 * 1024 + (size_t)row * 1024 + h * 64 + nf * 16 + l16] =
                    f2b(o_acc[m][nf][r] * inv);
        }
    }
}

// ---------------------------------------------------------------------------
extern "C" void kernel_launch(void* const* d_in, const int* in_sizes, int n_in,
                              void* d_out, int out_size, void* d_ws, size_t ws_size,
                              hipStream_t stream)
{
    const float* x   = (const float*)d_in[0];
    const float* wq  = (const float*)d_in[1];
    const float* bq  = (const float*)d_in[2];
    const float* wk  = (const float*)d_in[3];
    const float* bk  = (const float*)d_in[4];
    const float* wv  = (const float*)d_in[5];
    const float* bv  = (const float*)d_in[6];
    const float* wo  = (const float*)d_in[7];
    const float* bo  = (const float*)d_in[8];
    const float* w1  = (const float*)d_in[9];
    const float* b1  = (const float*)d_in[10];
    const float* w2  = (const float*)d_in[11];
    const float* b2  = (const float*)d_in[12];
    const float* g1  = (const float*)d_in[13];
    const float* be1 = (const float*)d_in[14];
    const float* g2  = (const float*)d_in[15];
    const float* be2 = (const float*)d_in[16];
    float* out = (float*)d_out;
    char*  ws  = (char*)d_ws;

    const int M = 4096, D = 1024, DFF = 4096;
    const size_t MB = 1 << 20;

    unsigned short* wqkvT = (unsigned short*)(ws + 0 * MB);   // [3072][1024] 6MB
    unsigned short* woT   = (unsigned short*)(ws + 6 * MB);   // 2MB
    unsigned short* w1T   = (unsigned short*)(ws + 8 * MB);   // 8MB
    unsigned short* w2T   = (unsigned short*)(ws + 16 * MB);  // 8MB
    unsigned short* ln    = (unsigned short*)(ws + 24 * MB);  // 8MB
    unsigned short* qkb   = (unsigned short*)(ws + 32 * MB);  // 16MB
    unsigned short* vbT   = (unsigned short*)(ws + 48 * MB);  // 8MB
    unsigned short* ao    = (unsigned short*)(ws + 56 * MB);  // 8MB
    unsigned short* ff1   = (unsigned short*)(ws + 32 * MB);  // 32MB (reuse)
    float*          x2    = (float*)(ws + 64 * MB);           // 16MB
    float*          bqkv  = (float*)(ws + 80 * MB);           // 12KB (pre-partials)
    unsigned short* pHi   = (unsigned short*)(ws + 80 * MB);  // slices 0,1 (16MB)
    unsigned short* pOlo  = (unsigned short*)(ws + 32 * MB);  // O-proj slices 2,3
    unsigned short* pFlo  = (unsigned short*)(ws + 0 * MB);   // FF2 slices 2,3

    // --- weight prep + bias concat + LN1 (one launch) ---
    prep_all_k<<<16396, 256, 0, stream>>>(wq, wk, wv, wo, w1, w2,
                                          wqkvT, woT, w1T, w2T,
                                          bq, bk, bv, bqkv,
                                          x, g1, be1, ln);
    // --- fused QKV projection: QK' -> qkb, V -> vbT (V^T) ---
    gemm256<2, 0><<<dim3(12, 16), 512, 0, stream>>>(
        ln, D, wqkvT, D, bqkv, qkb, vbT, 3072, D);
    // --- attention ---
    attn_kernel<<<dim3(16, 32), 256, 0, stream>>>(qkb, vbT, ao);
    // --- O projection split-K4 bf16 partials; reduce + residual + LN2 ---
    gemm256<5, 0><<<dim3(4, 16, 4), 512, 0, stream>>>(
        ao, D, woT, D, nullptr, pHi, pOlo, 1024, 256);
    reduce_ln_kernel<<<M, 256, 0, stream>>>(pHi, pOlo, bo, x, g2, be2, x2, ln);
    // --- FFN ---
    gemm256<0, 1><<<dim3(16, 16), 512, 0, stream>>>(
        ln, D, w1T, D, b1, ff1, nullptr, DFF, D);
    gemm256<5, 0><<<dim3(4, 16, 4), 512, 0, stream>>>(
        ff1, DFF, w2T, DFF, nullptr, pHi, pFlo, 1024, 1024);
    reduce_out4_k<<<4096, 256, 0, stream>>>(pHi, pFlo, b2, x2, out);
}